// Round 1
// baseline (487.057 us; speedup 1.0000x reference)
//
#include <hip/hip_runtime.h>
#include <hip/hip_bf16.h>

// BlockSparseLinear: out[N,OUT] = x[N,IN] . (W * blockmask)^T + bias
// N=8192, IN=4096, OUT=4096, BLOCKSIZE=32, mask (128,128) int32 {0,1}
//
// Round 5: 256x256 tile, 8 waves, 4-phase/K-tile deep pipeline with counted
// vmcnt (never 0 in loop), raw s_barrier (no implicit drain), setprio around
// MFMA clusters. XOR-swizzled LDS carried over from round 4. Mask skip on
// ds_read+MFMA only; staging unconditional (keeps per-wave vmcnt uniform).
//
// Chunk schedule per K-tile t (buf b=t&1), staging tile t+1 into buf b^1:
//   s0 (h0,p0): read A_lo+B_lo(t), issue A_lo(t+1), MFMA q00, vmcnt(4)  [drains B_hi(t)]
//   s1 (h0,p1): read B_hi(t),      issue B_lo(t+1), MFMA q01, vmcnt(4)  [drains A_hi(t)]
//   s2 (h1,p0): read A_hi(t),      issue B_hi(t+1), MFMA q10, (no wait)
//   s3 (h1,p1): -,                 issue A_hi(t+1), MFMA q11, vmcnt(4)  [drains A_lo,B_lo(t+1)]
// Each chunk = 2 loads/thread; max 8 in flight; every boundary wait leaves
// younger loads in flight (cp.async-style pipeline).

using bf16 = __hip_bfloat16;
typedef __attribute__((ext_vector_type(8))) short short8;   // 8 x bf16
typedef __attribute__((ext_vector_type(4))) short short4_t; // 4 x bf16
typedef __attribute__((ext_vector_type(4))) float f32x4;    // MFMA accumulator

#define N_ROWS 8192
#define IN     4096
#define OUT    4096
#define KB     128      // mask cols (IN/32)

#define BM 256
#define BO 256
#define BK 64           // row = 8 chunks of 8 bf16 (16 B each)
#define NT (IN / BK)    // 64 K-tiles

__device__ __forceinline__ short4_t cvt4_bf16(float a, float b, float c, float d) {
    union { short4_t s; bf16 h[4]; } u;
    u.h[0] = __float2bfloat16(a);
    u.h[1] = __float2bfloat16(b);
    u.h[2] = __float2bfloat16(c);
    u.h[3] = __float2bfloat16(d);
    return u.s;
}

// ---------------- Fused convert: X fp32->bf16 ; W fp32->bf16 masked ----------
__global__ __launch_bounds__(256)
void cvt_kernel(const float* __restrict__ X, const float* __restrict__ W,
                const int* __restrict__ mask,
                bf16* __restrict__ Xb, bf16* __restrict__ Wb) {
    int b = blockIdx.x;
    if (b < 32768) {
        size_t i = ((size_t)b * 256 + threadIdx.x) * 4;
        float4 d = *(const float4*)(X + i);
        *(short4_t*)(Xb + i) = cvt4_bf16(d.x, d.y, d.z, d.w);
    } else {
        size_t i = ((size_t)(b - 32768) * 256 + threadIdx.x) * 4;
        int row = (int)(i >> 12);          // /IN
        int col = (int)(i & 4095);         // %IN
        int mv  = mask[(row >> 5) * KB + (col >> 5)];
        short4_t p = {};
        if (mv != 0) {
            float4 d = *(const float4*)(W + i);
            p = cvt4_bf16(d.x, d.y, d.z, d.w);
        }
        *(short4_t*)(Wb + i) = p;
    }
}

// 16B global->LDS direct (width 16)
#define GLD(srcp, dstp) __builtin_amdgcn_global_load_lds(                     \
        (const __attribute__((address_space(1))) void*)(srcp),                \
        (__attribute__((address_space(3))) void*)(dstp), 16, 0, 0)

// A fragment reads: 4 rows x (kk chunk), swizzled slot = chunk ^ (row&7)
#define LD_A(DST, ROWBASE, KKCH)                                              \
    { _Pragma("unroll") for (int il = 0; il < 4; ++il) {                      \
        const int R = (ROWBASE) + il * 16 + lm;                               \
        DST[il] = *(const short8*)(pA + R * BK + ((((KKCH) + q) ^ xm) * 8)); } }

#define LD_B(DST, ROWBASE, KKCH)                                              \
    { _Pragma("unroll") for (int jj = 0; jj < 2; ++jj) {                      \
        const int R = (ROWBASE) + jj * 16 + lm;                               \
        DST[jj] = *(const short8*)(pB + R * BK + ((((KKCH) + q) ^ xm) * 8)); } }

#define MFMA4x2(I0, J0, AF, BF)                                               \
    { _Pragma("unroll") for (int il = 0; il < 4; ++il)                        \
      { _Pragma("unroll") for (int jj = 0; jj < 2; ++jj)                      \
          acc[(I0) + il][(J0) + jj] = __builtin_amdgcn_mfma_f32_16x16x32_bf16(\
              (AF)[il], (BF)[jj], acc[(I0) + il][(J0) + jj], 0, 0, 0); } }

__global__ __launch_bounds__(512, 2)
void bsl_gemm256_kernel(const bf16* __restrict__ Xb, const bf16* __restrict__ Wb,
                        const float* __restrict__ bias, const int* __restrict__ mask,
                        float* __restrict__ out)
{
    __shared__ bf16 sA[2][BM * BK];   // 2 x 32 KB
    __shared__ bf16 sB[2][BO * BK];   // 2 x 32 KB
    __shared__ int  sMask[8 * KB];    // 4 KB (8 mask rows for this o-tile)

    const int tid  = threadIdx.x;
    const int o0   = blockIdx.x * BO;   // x = o-tile: XCD gets 2 W-panels (L2-res)
    const int m0   = blockIdx.y * BM;
    const int wave = tid >> 6;
    const int lane = tid & 63;
    const int wr   = wave >> 2;        // 0..1  m-dim (rows wr*128..+127)
    const int wc   = wave & 3;         // 0..3  o-dim (cols wc*64..+63)

    const int lm = lane & 15;          // fragment row
    const int q  = lane >> 4;          // 0..3 -> 8-elem chunk within K=32
    const int xm = lm & 7;             // read-side swizzle xor

    // staging: one issue/wave = 8 rows x 8 chunks; lane -> (srow, slot)
    const int srow = lane >> 3;                  // 0..7
    const int schk = (lane & 7) ^ srow;          // swizzled source chunk
    const int ra0  = wave * 8;                       // A issue row (wave part)
    const int rb0  = (wave >> 2) * 64 + (wave & 3) * 8;  // B issue row

    for (int i = tid; i < 8 * KB; i += 512)
        sMask[i] = mask[(o0 >> 5) * KB + i];

    // ---- prologue: stage tile 0 into buffer 0, full drain once ----
    {
        const bf16* ax = Xb + (size_t)(m0 + srow) * IN + schk * 8;
        const bf16* bx = Wb + (size_t)(o0 + srow) * IN + schk * 8;
        GLD(ax + (size_t)(0   + ra0) * IN, &sA[0][(0   + ra0) * BK]);   // A_lo
        GLD(ax + (size_t)(128 + ra0) * IN, &sA[0][(128 + ra0) * BK]);
        GLD(bx + (size_t)(0   + rb0) * IN, &sB[0][(0   + rb0) * BK]);   // B_lo
        GLD(bx + (size_t)(128 + rb0) * IN, &sB[0][(128 + rb0) * BK]);
        GLD(bx + (size_t)(32  + rb0) * IN, &sB[0][(32  + rb0) * BK]);   // B_hi
        GLD(bx + (size_t)(160 + rb0) * IN, &sB[0][(160 + rb0) * BK]);
        GLD(ax + (size_t)(64  + ra0) * IN, &sA[0][(64  + ra0) * BK]);   // A_hi
        GLD(ax + (size_t)(192 + ra0) * IN, &sA[0][(192 + ra0) * BK]);
    }
    __syncthreads();   // publishes sMask + tile 0 (vmcnt(0) drain here only)

    f32x4 acc[8][4] = {};
    const int mrow0 = (wc * 2) * KB;       // mask row for j-pair 0 (p=0)
    const int mrow1 = (wc * 2 + 1) * KB;   // mask row for j-pair 1 (p=1)

    for (int t = 0; t < NT; ++t) {
        const int b = t & 1;
        const bf16* pA = sA[b];
        const bf16* pB = sB[b];
        bf16* nApt = sA[b ^ 1];
        bf16* nBpt = sB[b ^ 1];
        const int c0 = t * 2;
        // dummy wrap on last tile keeps vmcnt arithmetic + control flow uniform
        const size_t kN = (t + 1 < NT) ? (size_t)(t + 1) * BK : 0;
        const bf16* axn = Xb + (size_t)(m0 + srow) * IN + kN + schk * 8;
        const bf16* bxn = Wb + (size_t)(o0 + srow) * IN + kN + schk * 8;

        const int mv00 = sMask[mrow0 + c0];       // (p0, kk0)
        const int mv01 = sMask[mrow0 + c0 + 1];   // (p0, kk1)
        const int mv10 = sMask[mrow1 + c0];       // (p1, kk0)
        const int mv11 = sMask[mrow1 + c0 + 1];   // (p1, kk1)
        const int nA0 = mv00 | mv10;              // A kk0 needed?
        const int nA1 = mv01 | mv11;              // A kk1 needed?

        short8 a0[4], a1[4];                      // A frags, h-scope
        short8 b00[2], b01[2], b10[2], b11[2];    // B frags, tile-scope

        // ========== phase s0: h=0, p=0 ==========
        if (nA0) LD_A(a0, wr * 128, 0);
        if (nA1) LD_A(a1, wr * 128, 4);
        if (mv00) LD_B(b00, wc * 64, 0);
        if (mv01) LD_B(b01, wc * 64, 4);
        GLD(axn + (size_t)(0   + ra0) * IN, &nApt[(0   + ra0) * BK]);   // A_lo(t+1)
        GLD(axn + (size_t)(128 + ra0) * IN, &nApt[(128 + ra0) * BK]);
        __builtin_amdgcn_s_barrier();
        __builtin_amdgcn_s_setprio(1);
        if (mv00) MFMA4x2(0, 0, a0, b00);
        if (mv01) MFMA4x2(0, 0, a1, b01);
        __builtin_amdgcn_s_setprio(0);
        asm volatile("s_waitcnt vmcnt(4)");   // drains B_hi(t)
        __builtin_amdgcn_s_barrier();

        // ========== phase s1: h=0, p=1 ==========
        if (mv10) LD_B(b10, wc * 64 + 32, 0);
        if (mv11) LD_B(b11, wc * 64 + 32, 4);
        GLD(bxn + (size_t)(0   + rb0) * IN, &nBpt[(0   + rb0) * BK]);   // B_lo(t+1)
        GLD(bxn + (size_t)(128 + rb0) * IN, &nBpt[(128 + rb0) * BK]);
        __builtin_amdgcn_s_barrier();
        __builtin_amdgcn_s_setprio(1);
        if (mv10) MFMA4x2(0, 2, a0, b10);
        if (mv11) MFMA4x2(0, 2, a1, b11);
        __builtin_amdgcn_s_setprio(0);
        asm volatile("s_waitcnt vmcnt(4)");   // drains A_hi(t)
        __builtin_amdgcn_s_barrier();

        // ========== phase s2: h=1, p=0 ==========
        if (nA0) LD_A(a0, wr * 128 + 64, 0);
        if (nA1) LD_A(a1, wr * 128 + 64, 4);
        GLD(bxn + (size_t)(32  + rb0) * IN, &nBpt[(32  + rb0) * BK]);   // B_hi(t+1)
        GLD(bxn + (size_t)(160 + rb0) * IN, &nBpt[(160 + rb0) * BK]);
        __builtin_amdgcn_s_barrier();
        __builtin_amdgcn_s_setprio(1);
        if (mv00) MFMA4x2(4, 0, a0, b00);
        if (mv01) MFMA4x2(4, 0, a1, b01);
        __builtin_amdgcn_s_setprio(0);
        __builtin_amdgcn_s_barrier();         // no wait needed this boundary

        // ========== phase s3: h=1, p=1 ==========
        GLD(axn + (size_t)(64  + ra0) * IN, &nApt[(64  + ra0) * BK]);   // A_hi(t+1)
        GLD(axn + (size_t)(192 + ra0) * IN, &nApt[(192 + ra0) * BK]);
        __builtin_amdgcn_s_barrier();
        __builtin_amdgcn_s_setprio(1);
        if (mv10) MFMA4x2(4, 2, a0, b10);
        if (mv11) MFMA4x2(4, 2, a1, b11);
        __builtin_amdgcn_s_setprio(0);
        asm volatile("s_waitcnt vmcnt(4)");   // drains A_lo(t+1), B_lo(t+1)
        __builtin_amdgcn_s_barrier();
    }

    asm volatile("s_waitcnt vmcnt(0)");  // no pending LDS DMA past kernel end

    // ---- epilogue: C/D layout col=lane&15, row=(lane>>4)*4+reg; fp32 out ----
    const int rbase = (lane >> 4) * 4;
    const int ccol  = lane & 15;
    #pragma unroll
    for (int j = 0; j < 4; ++j) {
        int o = o0 + wc * 64 + j * 16 + ccol;
        float bv = bias[o];
        #pragma unroll
        for (int i = 0; i < 8; ++i) {
            #pragma unroll
            for (int r = 0; r < 4; ++r) {
                int m = m0 + wr * 128 + i * 16 + rbase + r;
                out[(size_t)m * OUT + o] = acc[i][j][r] + bv;
            }
        }
    }
}

// ---------------- Fallback (round-2 single-pass, known-good) ----------------
#define FBM 128
#define FBO 128
#define FBK 64
#define LDK (FBK + 8)
__global__ __launch_bounds__(256, 2)
void bsl_fallback_kernel(const float* __restrict__ X, const float* __restrict__ W,
                         const float* __restrict__ bias, const int* __restrict__ mask,
                         float* __restrict__ out)
{
    __shared__ bf16 sA[FBM * LDK];
    __shared__ bf16 sB[FBO * LDK];
    const int tid = threadIdx.x;
    const int m0 = blockIdx.x * FBM, o0 = blockIdx.y * FBO;
    const int wave = tid >> 6, lane = tid & 63;
    const int wm = (wave & 1) * 64, wo = (wave >> 1) * 64;
    const int lm = lane & 15, lk = (lane >> 4) * 8;
    f32x4 acc[4][4] = {};
    for (int k0 = 0; k0 < IN; k0 += FBK) {
        #pragma unroll
        for (int v = 0; v < 8; ++v) {
            int e = (v * 256 + tid) * 4, row = e >> 6, col = e & 63;
            float4 d = *(const float4*)(X + (size_t)(m0 + row) * IN + (k0 + col));
            *(short4_t*)(sA + row * LDK + col) = cvt4_bf16(d.x, d.y, d.z, d.w);
        }
        #pragma unroll
        for (int v = 0; v < 8; ++v) {
            int e = (v * 256 + tid) * 4, row = e >> 6, col = e & 63;
            int mv = mask[((o0 + row) >> 5) * KB + ((k0 + col) >> 5)];
            short4_t p = {};
            if (mv != 0) {
                float4 d = *(const float4*)(W + (size_t)(o0 + row) * IN + (k0 + col));
                p = cvt4_bf16(d.x, d.y, d.z, d.w);
            }
            *(short4_t*)(sB + row * LDK + col) = p;
        }
        __syncthreads();
        #pragma unroll
        for (int kk = 0; kk < FBK; kk += 32) {
            short8 af[4], bfr[4];
            #pragma unroll
            for (int i = 0; i < 4; ++i)
                af[i] = *(const short8*)(sA + (wm + i * 16 + lm) * LDK + kk + lk);
            #pragma unroll
            for (int j = 0; j < 4; ++j)
                bfr[j] = *(const short8*)(sB + (wo + j * 16 + lm) * LDK + kk + lk);
            #pragma unroll
            for (int i = 0; i < 4; ++i)
                #pragma unroll
                for (int j = 0; j < 4; ++j)
                    acc[i][j] = __builtin_amdgcn_mfma_f32_16x16x32_bf16(
                        af[i], bfr[j], acc[i][j], 0, 0, 0);
        }
        __syncthreads();
    }
    const int rbase = (lane >> 4) * 4, ccol = lane & 15;
    #pragma unroll
    for (int j = 0; j < 4; ++j) {
        int o = o0 + wo + j * 16 + ccol;
        float bv = bias[o];
        #pragma unroll
        for (int i = 0; i < 4; ++i)
            #pragma unroll
            for (int r = 0; r < 4; ++r)
                out[(size_t)(m0 + wm + i * 16 + rbase + r) * OUT + o] = acc[i][j][r] + bv;
    }
}

extern "C" void kernel_launch(void* const* d_in, const int* in_sizes, int n_in,
                              void* d_out, int out_size, void* d_ws, size_t ws_size,
                              hipStream_t stream) {
    const float* x    = (const float*)d_in[0];   // (8192, 4096) fp32
    const float* w    = (const float*)d_in[1];   // (4096, 4096) fp32
    const float* bias = (const float*)d_in[2];   // (4096,) fp32
    const int*   mask = (const int*)  d_in[3];   // (128, 128) int32
    float* out = (float*)d_out;                  // (8192, 4096) fp32

    const size_t xb_bytes = (size_t)N_ROWS * IN * sizeof(bf16);  // 64 MB
    const size_t wb_bytes = (size_t)OUT * IN * sizeof(bf16);     // 32 MB

    if (ws_size >= xb_bytes + wb_bytes) {
        bf16* xb = (bf16*)d_ws;
        bf16* wb = (bf16*)((char*)d_ws + xb_bytes);
        const int xblk = (int)((N_ROWS * (size_t)IN) / 1024);    // 32768
        const int wblk = (int)((OUT * (size_t)IN) / 1024);       // 16384
        cvt_kernel<<<xblk + wblk, 256, 0, stream>>>(x, w, mask, xb, wb);
        dim3 grid(OUT / BO, N_ROWS / BM);        // (16, 32)
        bsl_gemm256_kernel<<<grid, 512, 0, stream>>>(xb, wb, bias, mask, out);
    } else {
        dim3 grid(N_ROWS / FBM, OUT / FBO);
        bsl_fallback_kernel<<<grid, 256, 0, stream>>>(x, w, bias, mask, out);
    }
}